// Round 4
// baseline (383.264 us; speedup 1.0000x reference)
//
#include <hip/hip_runtime.h>
#include <math.h>

// Shapes: encoded [B=4, C=256, 256, 256] fp32, masks [B,1,256,256] int32 in [0,32]
// w1 [256,128], b1 [128], w2 [128,4], b2 [4] -> out [B,32,4] fp32
#define BATCH   4
#define CH      256
#define PIX     65536
#define NIDS    33
#define NOBJ    32
#define SSPLIT  2
#define F4_SLICE (PIX / 4)              // float4s per (b,c) slice = 16384
#define F4_PER_S (F4_SLICE / SSPLIT)    // 8192
#define ITERS2   (F4_PER_S / 512)       // 16: 512 float4s (2048 px) per block-iter

typedef float f32x4 __attribute__((ext_vector_type(4)));

__device__ __forceinline__ unsigned f2u_nonneg(float x) {
    // x >= 0: raw-bit unsigned order == float order
    union { float f; unsigned u; } c; c.f = x; return c.u;
}
__device__ __forceinline__ float u2f(unsigned u) {
    union { float f; unsigned u; } c; c.u = u; return c.f;
}

// ---------------------------------------------------------------------------
// Kernel 0: pack int32 ids (0..32) into bytes; word i <- pixels 4i..4i+3.
// Mask resident set 4 MB -> 256 KB (L2-hot on every XCD), traffic /4.
// ---------------------------------------------------------------------------
__global__ __launch_bounds__(256) void pack_masks_kernel(
    const int* __restrict__ masks, unsigned int* __restrict__ maskw)
{
    const int idx = blockIdx.x * 256 + threadIdx.x;
    const int4 v = ((const int4*)masks)[idx];
    maskw[idx] = (unsigned)v.x | ((unsigned)v.y << 8) |
                 ((unsigned)v.z << 16) | ((unsigned)v.w << 24);
}

// ---------------------------------------------------------------------------
// Kernel 1: segmented max via LDS atomic max (ds_max_u32, fire-and-forget).
// Values clamped at 0 on load (reference applies maximum(seg,0)), so
// non-negative float order == u32 bit order; empty segments -> 0.0f.
// VMEM-depth version: 8 px/thread/iter (two float4 + one uint2 mask word),
// explicit 1-ahead pipeline -> ~5 KB in flight per wave (~80 KB/CU), plain
// (non-NT) loads. Bins smax[id*256+t]: every lane hits bank t%32 -> fixed
// 2-way aliasing (free on gfx950).
// ---------------------------------------------------------------------------
__global__ __launch_bounds__(256, 1) void segmax_kernel(
    const float*        __restrict__ encoded,
    const unsigned int* __restrict__ maskw,
    float*              __restrict__ pooledP)   // [SSPLIT, B, NOBJ, CH]
{
    __shared__ unsigned smax[NIDS * 256];
    __shared__ unsigned partial[NOBJ * 8];

    const int t     = threadIdx.x;
    const int slice = blockIdx.x >> 1;    // b*256 + c
    const int s     = blockIdx.x & 1;
    const int b     = slice >> 8;
    const int c     = slice & 255;

    #pragma unroll
    for (int i = 0; i < NIDS; ++i)
        smax[i * 256 + t] = 0u;           // 0u == 0.0f: the clamp floor
    __syncthreads();

    const f32x4* __restrict__ vals =
        (const f32x4*)encoded + (size_t)slice * F4_SLICE + (size_t)s * F4_PER_S;
    const uint2* __restrict__ mw2 =
        (const uint2*)(maskw + (size_t)b * F4_SLICE + (size_t)s * F4_PER_S);

    // 1-ahead software pipeline; two float4 + one uint2 per thread per iter
    f32x4 v0 = vals[2 * t];
    f32x4 v1 = vals[2 * t + 1];
    uint2 m  = mw2[t];

    #pragma unroll 2
    for (int it = 0; it < ITERS2; ++it) {
        f32x4 nv0, nv1;
        uint2 nm = make_uint2(0u, 0u);
        if (it + 1 < ITERS2) {
            const int base = (it + 1) * 512 + 2 * t;
            nv0 = vals[base];
            nv1 = vals[base + 1];
            nm  = mw2[(it + 1) * 256 + t];
        }
        atomicMax(&smax[((m.x      ) & 255) * 256 + t], f2u_nonneg(fmaxf(v0.x, 0.0f)));
        atomicMax(&smax[((m.x >>  8) & 255) * 256 + t], f2u_nonneg(fmaxf(v0.y, 0.0f)));
        atomicMax(&smax[((m.x >> 16) & 255) * 256 + t], f2u_nonneg(fmaxf(v0.z, 0.0f)));
        atomicMax(&smax[((m.x >> 24)      ) * 256 + t], f2u_nonneg(fmaxf(v0.w, 0.0f)));
        atomicMax(&smax[((m.y      ) & 255) * 256 + t], f2u_nonneg(fmaxf(v1.x, 0.0f)));
        atomicMax(&smax[((m.y >>  8) & 255) * 256 + t], f2u_nonneg(fmaxf(v1.y, 0.0f)));
        atomicMax(&smax[((m.y >> 16) & 255) * 256 + t], f2u_nonneg(fmaxf(v1.z, 0.0f)));
        atomicMax(&smax[((m.y >> 24)      ) * 256 + t], f2u_nonneg(fmaxf(v1.w, 0.0f)));
        v0 = nv0; v1 = nv1; m = nm;
    }
    __syncthreads();

    // Stage 1: 256 threads = 32 ids x 8 groups of 32 entries; per-lane
    // rotation (j+t)&31 keeps the 64 lanes spread over banks.
    {
        const int id   = 1 + (t >> 3);    // ids 1..32 (drop background 0)
        const int g    = t & 7;
        const int base = id * 256 + g * 32;
        unsigned mx = 0u;
        #pragma unroll
        for (int j = 0; j < 32; ++j) {
            const int jj = (j + t) & 31;
            mx = max(mx, smax[base + jj]);
        }
        partial[(id - 1) * 8 + g] = mx;
    }
    __syncthreads();

    if (t < NOBJ) {
        unsigned mx = 0u;
        #pragma unroll
        for (int g = 0; g < 8; ++g) mx = max(mx, partial[t * 8 + g]);
        pooledP[((size_t)s * BATCH * NOBJ + (size_t)b * NOBJ + t) * CH + c] = u2f(mx);
    }
}

// ---------------------------------------------------------------------------
// Kernel 2: merge SSPLIT partials (already >= 0), then tiny MLP + sigmoid.
// One block (256 thr) per pooled row; split-K by 2 for layer 1.
// ---------------------------------------------------------------------------
__global__ __launch_bounds__(256, 1) void mlp_kernel(
    const float* __restrict__ pooledP,
    const float* __restrict__ w1, const float* __restrict__ b1,
    const float* __restrict__ w2, const float* __restrict__ b2,
    float*       __restrict__ out)
{
    __shared__ float row[CH];
    __shared__ float hpart[256];
    __shared__ float h[128];
    const int t = threadIdx.x;
    const int r = blockIdx.x;          // 0..127 = b*32 + n

    {
        const float p0 = pooledP[(size_t)r * CH + t];
        const float p1 = pooledP[((size_t)BATCH * NOBJ + r) * CH + t];
        row[t] = fmaxf(p0, p1);        // both halves already clamped at 0
    }
    __syncthreads();

    {
        const int j  = t & 127;
        const int kh = t >> 7;         // K-half 0/1
        float acc = (kh == 0) ? b1[j] : 0.0f;
        const int kbase = kh * 128;
        #pragma unroll 8
        for (int i = 0; i < 128; ++i)
            acc = fmaf(row[kbase + i], w1[(kbase + i) * 128 + j], acc);
        hpart[t] = acc;
    }
    __syncthreads();
    if (t < 128) h[t] = hpart[t] + hpart[t + 128];
    __syncthreads();

    if (t < 4) {
        float a = b2[t];
        #pragma unroll 8
        for (int i = 0; i < 128; ++i)
            a = fmaf(h[i], w2[i * 4 + t], a);
        out[(size_t)r * 4 + t] = 1.0f / (1.0f + expf(-a));
    }
}

extern "C" void kernel_launch(void* const* d_in, const int* in_sizes, int n_in,
                              void* d_out, int out_size, void* d_ws, size_t ws_size,
                              hipStream_t stream) {
    // setup_inputs() dict order: encoded, w1, b1, w2, b2, masks
    const float* encoded = (const float*)d_in[0];
    const float* w1      = (const float*)d_in[1];
    const float* b1      = (const float*)d_in[2];
    const float* w2      = (const float*)d_in[3];
    const float* b2      = (const float*)d_in[4];
    const int*   masks   = (const int*)  d_in[5];
    float* out = (float*)d_out;

    // workspace layout: [0, 256KB) packed masks, then pooled partials
    unsigned int* maskw   = (unsigned int*)d_ws;              // B*PIX/4 words
    float*        pooledP = (float*)d_ws + BATCH * F4_SLICE;  // [2, B, NOBJ, CH]

    pack_masks_kernel<<<BATCH * PIX / 4 / 256, 256, 0, stream>>>(masks, maskw);
    segmax_kernel<<<BATCH * CH * SSPLIT, 256, 0, stream>>>(encoded, maskw, pooledP);
    mlp_kernel<<<BATCH * NOBJ, 256, 0, stream>>>(pooledP, w1, b1, w2, b2, out);
}

// Round 5
// 379.704 us; speedup vs baseline: 1.0094x; 1.0094x over previous
//
#include <hip/hip_runtime.h>
#include <math.h>

// Shapes: encoded [B=4, C=256, 256, 256] fp32, masks [B,1,256,256] int32 in [0,32]
// w1 [256,128], b1 [128], w2 [128,4], b2 [4] -> out [B,32,4] fp32
#define BATCH   4
#define CH      256
#define PIX     65536
#define NIDS    33
#define NOBJ    32
#define SSPLIT  2
#define F4_SLICE (PIX / 4)              // float4s per (b,c) slice = 16384
#define F4_PER_S (F4_SLICE / SSPLIT)    // 8192
#define ITERS    (F4_PER_S / 256)       // 32

typedef float f32x4 __attribute__((ext_vector_type(4)));

__device__ __forceinline__ unsigned f2u_nonneg(float x) {
    // x >= 0: raw-bit unsigned order == float order
    union { float f; unsigned u; } c; c.f = x; return c.u;
}
__device__ __forceinline__ float u2f(unsigned u) {
    union { float f; unsigned u; } c; c.u = u; return c.f;
}

// ---------------------------------------------------------------------------
// Kernel 0: pack int32 ids (0..32) into bytes; word i <- pixels 4i..4i+3.
// Mask resident set 4 MB -> 256 KB (L2-hot on every XCD), traffic /4.
// ---------------------------------------------------------------------------
__global__ __launch_bounds__(256) void pack_masks_kernel(
    const int* __restrict__ masks, unsigned int* __restrict__ maskw)
{
    const int idx = blockIdx.x * 256 + threadIdx.x;
    const int4 v = ((const int4*)masks)[idx];
    maskw[idx] = (unsigned)v.x | ((unsigned)v.y << 8) |
                 ((unsigned)v.z << 16) | ((unsigned)v.w << 24);
}

// ---------------------------------------------------------------------------
// Kernel 1: segmented max via LDS atomic max (ds_max_u32, fire-and-forget).
// A/B vs R3: ONLY change is plain loads instead of __builtin_nontemporal_load.
// Identical grid (2048x256), identical 16B/lane unit-stride pattern,
// identical unroll, identical atomics. If this is neutral, the DS atomic
// pipe is the bottleneck by elimination; if it wins, NT was capping BW.
// ---------------------------------------------------------------------------
__global__ __launch_bounds__(256, 1) void segmax_kernel(
    const float*        __restrict__ encoded,
    const unsigned int* __restrict__ maskw,
    float*              __restrict__ pooledP)   // [SSPLIT, B, NOBJ, CH]
{
    __shared__ unsigned smax[NIDS * 256];
    __shared__ unsigned partial[NOBJ * 8];

    const int t     = threadIdx.x;
    const int slice = blockIdx.x >> 1;    // b*256 + c
    const int s     = blockIdx.x & 1;
    const int b     = slice >> 8;
    const int c     = slice & 255;

    #pragma unroll
    for (int i = 0; i < NIDS; ++i)
        smax[i * 256 + t] = 0u;           // 0u == 0.0f: the clamp floor
    __syncthreads();

    const f32x4* __restrict__ vals =
        (const f32x4*)encoded + (size_t)slice * F4_SLICE + (size_t)s * F4_PER_S;
    const unsigned int* __restrict__ mw =
        maskw + (size_t)b * F4_SLICE + (size_t)s * F4_PER_S;

    // 1-ahead prefetch; body has no LDS waits so VMEM stays deeply in flight
    f32x4 v = vals[t];
    unsigned int m = mw[t];

    #pragma unroll 4
    for (int it = 0; it < ITERS; ++it) {
        f32x4 nv;
        unsigned int nm = 0;
        if (it + 1 < ITERS) {
            nv = vals[(it + 1) * 256 + t];
            nm = mw[(it + 1) * 256 + t];
        }
        atomicMax(&smax[((m      ) & 255) * 256 + t], f2u_nonneg(fmaxf(v.x, 0.0f)));
        atomicMax(&smax[((m >>  8) & 255) * 256 + t], f2u_nonneg(fmaxf(v.y, 0.0f)));
        atomicMax(&smax[((m >> 16) & 255) * 256 + t], f2u_nonneg(fmaxf(v.z, 0.0f)));
        atomicMax(&smax[((m >> 24)      ) * 256 + t], f2u_nonneg(fmaxf(v.w, 0.0f)));
        v = nv; m = nm;
    }
    __syncthreads();

    // Stage 1: 256 threads = 32 ids x 8 groups of 32 entries; per-lane
    // rotation (j+t)&31 keeps the 64 lanes spread over banks.
    {
        const int id   = 1 + (t >> 3);    // ids 1..32 (drop background 0)
        const int g    = t & 7;
        const int base = id * 256 + g * 32;
        unsigned mx = 0u;
        #pragma unroll
        for (int j = 0; j < 32; ++j) {
            const int jj = (j + t) & 31;
            mx = max(mx, smax[base + jj]);
        }
        partial[(id - 1) * 8 + g] = mx;
    }
    __syncthreads();

    if (t < NOBJ) {
        unsigned mx = 0u;
        #pragma unroll
        for (int g = 0; g < 8; ++g) mx = max(mx, partial[t * 8 + g]);
        pooledP[((size_t)s * BATCH * NOBJ + (size_t)b * NOBJ + t) * CH + c] = u2f(mx);
    }
}

// ---------------------------------------------------------------------------
// Kernel 2: merge SSPLIT partials (already >= 0), then tiny MLP + sigmoid.
// One block (256 thr) per pooled row; split-K by 2 for layer 1.
// ---------------------------------------------------------------------------
__global__ __launch_bounds__(256, 1) void mlp_kernel(
    const float* __restrict__ pooledP,
    const float* __restrict__ w1, const float* __restrict__ b1,
    const float* __restrict__ w2, const float* __restrict__ b2,
    float*       __restrict__ out)
{
    __shared__ float row[CH];
    __shared__ float hpart[256];
    __shared__ float h[128];
    const int t = threadIdx.x;
    const int r = blockIdx.x;          // 0..127 = b*32 + n

    {
        const float p0 = pooledP[(size_t)r * CH + t];
        const float p1 = pooledP[((size_t)BATCH * NOBJ + r) * CH + t];
        row[t] = fmaxf(p0, p1);        // both halves already clamped at 0
    }
    __syncthreads();

    {
        const int j  = t & 127;
        const int kh = t >> 7;         // K-half 0/1
        float acc = (kh == 0) ? b1[j] : 0.0f;
        const int kbase = kh * 128;
        #pragma unroll 8
        for (int i = 0; i < 128; ++i)
            acc = fmaf(row[kbase + i], w1[(kbase + i) * 128 + j], acc);
        hpart[t] = acc;
    }
    __syncthreads();
    if (t < 128) h[t] = hpart[t] + hpart[t + 128];
    __syncthreads();

    if (t < 4) {
        float a = b2[t];
        #pragma unroll 8
        for (int i = 0; i < 128; ++i)
            a = fmaf(h[i], w2[i * 4 + t], a);
        out[(size_t)r * 4 + t] = 1.0f / (1.0f + expf(-a));
    }
}

extern "C" void kernel_launch(void* const* d_in, const int* in_sizes, int n_in,
                              void* d_out, int out_size, void* d_ws, size_t ws_size,
                              hipStream_t stream) {
    // setup_inputs() dict order: encoded, w1, b1, w2, b2, masks
    const float* encoded = (const float*)d_in[0];
    const float* w1      = (const float*)d_in[1];
    const float* b1      = (const float*)d_in[2];
    const float* w2      = (const float*)d_in[3];
    const float* b2      = (const float*)d_in[4];
    const int*   masks   = (const int*)  d_in[5];
    float* out = (float*)d_out;

    // workspace layout: [0, 256KB) packed masks, then pooled partials
    unsigned int* maskw   = (unsigned int*)d_ws;              // B*PIX/4 words
    float*        pooledP = (float*)d_ws + BATCH * F4_SLICE;  // [2, B, NOBJ, CH]

    pack_masks_kernel<<<BATCH * PIX / 4 / 256, 256, 0, stream>>>(masks, maskw);
    segmax_kernel<<<BATCH * CH * SSPLIT, 256, 0, stream>>>(encoded, maskw, pooledP);
    mlp_kernel<<<BATCH * NOBJ, 256, 0, stream>>>(pooledP, w1, b1, w2, b2, out);
}

// Round 6
// 354.938 us; speedup vs baseline: 1.0798x; 1.0698x over previous
//
#include <hip/hip_runtime.h>
#include <math.h>

// Shapes: encoded [B=4, C=256, 256, 256] fp32, masks [B,1,256,256] int32 in [0,32]
// w1 [256,128], b1 [128], w2 [128,4], b2 [4] -> out [B,32,4] fp32
#define BATCH   4
#define CH      256
#define PIX     65536
#define NIDS    33
#define NOBJ    32
#define SSPLIT  2
#define F4_SLICE (PIX / 4)              // float4s per (b,c) slice = 16384
#define F4_PER_S (F4_SLICE / SSPLIT)    // 8192
#define ITERS    (F4_PER_S / 256)       // 32

typedef float f32x4 __attribute__((ext_vector_type(4)));

__device__ __forceinline__ unsigned f2u_nonneg(float x) {
    // x >= 0: raw-bit unsigned order == float order
    union { float f; unsigned u; } c; c.f = x; return c.u;
}
__device__ __forceinline__ float u2f(unsigned u) {
    union { float f; unsigned u; } c; c.u = u; return c.f;
}

// ---------------------------------------------------------------------------
// Kernel 0: pack int32 ids (0..32) into bytes; word i <- pixels 4i..4i+3.
// ---------------------------------------------------------------------------
__global__ __launch_bounds__(256) void pack_masks_kernel(
    const int* __restrict__ masks, unsigned int* __restrict__ maskw)
{
    const int idx = blockIdx.x * 256 + threadIdx.x;
    const int4 v = ((const int4*)masks)[idx];
    maskw[idx] = (unsigned)v.x | ((unsigned)v.y << 8) |
                 ((unsigned)v.z << 16) | ((unsigned)v.w << 24);
}

// ---------------------------------------------------------------------------
// Kernel 1: segmented max via LDS atomic max. SINGLE CHANGE vs R3 (best):
// bin columns shared by thread PAIRS (col = t>>1) -> smax 33x128 u32 =
// 16.9 KB (was 33.8 KB) -> 8 blocks/CU = 32 waves/CU (was 16), doubling
// VMEM in-flight capacity. Sharing is safe because ds_max_u32 is atomic;
// per op each bank sees 2 lanes at ONE address (free 2-way case).
// NT loads restored per R5's A/B (NT beats plain by ~22 us).
// ---------------------------------------------------------------------------
__global__ __launch_bounds__(256, 8) void segmax_kernel(
    const float*        __restrict__ encoded,
    const unsigned int* __restrict__ maskw,
    float*              __restrict__ pooledP)   // [SSPLIT, B, NOBJ, CH]
{
    __shared__ unsigned smax[NIDS * 128];
    __shared__ unsigned partial[NOBJ * 8];

    const int t     = threadIdx.x;
    const int col   = t >> 1;             // two threads share a bin column
    const int slice = blockIdx.x >> 1;    // b*256 + c
    const int s     = blockIdx.x & 1;
    const int b     = slice >> 8;
    const int c     = slice & 255;

    // init 33*128 = 4224 words with 256 threads
    #pragma unroll
    for (int k = 0; k < 16; ++k)
        smax[k * 256 + t] = 0u;           // 0u == 0.0f: the clamp floor
    if (t < 128) smax[16 * 256 + t] = 0u;
    __syncthreads();

    const f32x4* __restrict__ vals =
        (const f32x4*)encoded + (size_t)slice * F4_SLICE + (size_t)s * F4_PER_S;
    const unsigned int* __restrict__ mw =
        maskw + (size_t)b * F4_SLICE + (size_t)s * F4_PER_S;

    // 1-ahead prefetch; body has no LDS waits so VMEM stays deeply in flight
    f32x4 v = __builtin_nontemporal_load(vals + t);
    unsigned int m = mw[t];

    #pragma unroll 4
    for (int it = 0; it < ITERS; ++it) {
        f32x4 nv;
        unsigned int nm = 0;
        if (it + 1 < ITERS) {
            nv = __builtin_nontemporal_load(vals + (it + 1) * 256 + t);
            nm = mw[(it + 1) * 256 + t];
        }
        atomicMax(&smax[((m      ) & 255) * 128 + col], f2u_nonneg(fmaxf(v.x, 0.0f)));
        atomicMax(&smax[((m >>  8) & 255) * 128 + col], f2u_nonneg(fmaxf(v.y, 0.0f)));
        atomicMax(&smax[((m >> 16) & 255) * 128 + col], f2u_nonneg(fmaxf(v.z, 0.0f)));
        atomicMax(&smax[((m >> 24)      ) * 128 + col], f2u_nonneg(fmaxf(v.w, 0.0f)));
        v = nv; m = nm;
    }
    __syncthreads();

    // Stage 1: 256 threads = 32 ids x 8 groups of 16 entries; per-lane
    // rotation (j+t)&15 spreads banks.
    {
        const int id   = 1 + (t >> 3);    // ids 1..32 (drop background 0)
        const int g    = t & 7;
        const int base = id * 128 + g * 16;
        unsigned mx = 0u;
        #pragma unroll
        for (int j = 0; j < 16; ++j) {
            const int jj = (j + t) & 15;
            mx = max(mx, smax[base + jj]);
        }
        partial[(id - 1) * 8 + g] = mx;
    }
    __syncthreads();

    if (t < NOBJ) {
        unsigned mx = 0u;
        #pragma unroll
        for (int g = 0; g < 8; ++g) mx = max(mx, partial[t * 8 + g]);
        pooledP[((size_t)s * BATCH * NOBJ + (size_t)b * NOBJ + t) * CH + c] = u2f(mx);
    }
}

// ---------------------------------------------------------------------------
// Kernel 2: merge SSPLIT partials (already >= 0), then tiny MLP + sigmoid.
// ---------------------------------------------------------------------------
__global__ __launch_bounds__(256, 1) void mlp_kernel(
    const float* __restrict__ pooledP,
    const float* __restrict__ w1, const float* __restrict__ b1,
    const float* __restrict__ w2, const float* __restrict__ b2,
    float*       __restrict__ out)
{
    __shared__ float row[CH];
    __shared__ float hpart[256];
    __shared__ float h[128];
    const int t = threadIdx.x;
    const int r = blockIdx.x;          // 0..127 = b*32 + n

    {
        const float p0 = pooledP[(size_t)r * CH + t];
        const float p1 = pooledP[((size_t)BATCH * NOBJ + r) * CH + t];
        row[t] = fmaxf(p0, p1);        // both halves already clamped at 0
    }
    __syncthreads();

    {
        const int j  = t & 127;
        const int kh = t >> 7;         // K-half 0/1
        float acc = (kh == 0) ? b1[j] : 0.0f;
        const int kbase = kh * 128;
        #pragma unroll 8
        for (int i = 0; i < 128; ++i)
            acc = fmaf(row[kbase + i], w1[(kbase + i) * 128 + j], acc);
        hpart[t] = acc;
    }
    __syncthreads();
    if (t < 128) h[t] = hpart[t] + hpart[t + 128];
    __syncthreads();

    if (t < 4) {
        float a = b2[t];
        #pragma unroll 8
        for (int i = 0; i < 128; ++i)
            a = fmaf(h[i], w2[i * 4 + t], a);
        out[(size_t)r * 4 + t] = 1.0f / (1.0f + expf(-a));
    }
}

extern "C" void kernel_launch(void* const* d_in, const int* in_sizes, int n_in,
                              void* d_out, int out_size, void* d_ws, size_t ws_size,
                              hipStream_t stream) {
    // setup_inputs() dict order: encoded, w1, b1, w2, b2, masks
    const float* encoded = (const float*)d_in[0];
    const float* w1      = (const float*)d_in[1];
    const float* b1      = (const float*)d_in[2];
    const float* w2      = (const float*)d_in[3];
    const float* b2      = (const float*)d_in[4];
    const int*   masks   = (const int*)  d_in[5];
    float* out = (float*)d_out;

    // workspace layout: [0, 256KB) packed masks, then pooled partials
    unsigned int* maskw   = (unsigned int*)d_ws;              // B*PIX/4 words
    float*        pooledP = (float*)d_ws + BATCH * F4_SLICE;  // [2, B, NOBJ, CH]

    pack_masks_kernel<<<BATCH * PIX / 4 / 256, 256, 0, stream>>>(masks, maskw);
    segmax_kernel<<<BATCH * CH * SSPLIT, 256, 0, stream>>>(encoded, maskw, pooledP);
    mlp_kernel<<<BATCH * NOBJ, 256, 0, stream>>>(pooledP, w1, b1, w2, b2, out);
}